// Round 13
// baseline (387.867 us; speedup 1.0000x reference)
//
#include <hip/hip_runtime.h>
#include <stdint.h>
#include <stddef.h>

// ---------- types ----------
typedef _Float16 half_t;
typedef half_t half8  __attribute__((ext_vector_type(8)));
typedef half_t half4v __attribute__((ext_vector_type(4)));
typedef float  f32x4  __attribute__((ext_vector_type(4)));

__device__ __forceinline__ float fast_sigmoid(float x) {
    float e = __builtin_amdgcn_exp2f(-1.44269504f * x);
    return __builtin_amdgcn_rcpf(1.0f + e);
}
__device__ __forceinline__ float fast_tanh(float x) {
    float e = __builtin_amdgcn_exp2f(2.88539008f * x);
    return 1.0f - 2.0f * __builtin_amdgcn_rcpf(1.0f + e);
}

// ---------------------------------------------------------------------------
// Prep: W [1024][256] f32 row-major -> MFMA-B fragment order, f16.
// Bijection (contiguous k): lane l, elem e of tile (T,kt) holds
//   B[k = kt*32 + (l>>4)*8 + e, j = T*16 + (l&15)].
// Element offset of (T,kt,l): T*4096 + kt*512 + l*8.
// A-fragments from LDS use the SAME mapping (validated R1-R12, absmax 2e-3).
// ---------------------------------------------------------------------------
__global__ __launch_bounds__(64) void shuffle_w_kernel(
    const float* __restrict__ W, half_t* __restrict__ out)
{
    const int blk = blockIdx.x;         // 512 = 64 T * 8 kt
    const int T = blk >> 3, kt = blk & 7;
    const int l = threadIdx.x;
    const int j = T * 16 + (l & 15);
    const int k0 = kt * 32 + ((l >> 4) << 3);
    half8 v;
#pragma unroll
    for (int e = 0; e < 8; ++e) v[e] = (half_t)W[j * 256 + k0 + e];
    *reinterpret_cast<half8*>(out + (size_t)(blk * 64 + l) * 8) = v;
}

// ---------------------------------------------------------------------------
// 2-gate-group GEMM pass (8 N-tiles: 2 groups x 4 j-tiles), M=32 (2 mt).
// bp0/bp1: lane-adjusted base pointers of the two gate groups' tile rows.
// kt loop pinned (unroll 1 + sched_barrier, R4-R12 proven anti-spill) with
// B double-buffer: b(kt+1) issued before MFMA(kt) so L2 latency hides.
// In-flight: acc 64 + bA/bB 64 + a 8 + addr ~12.
// ---------------------------------------------------------------------------
__device__ __forceinline__ void gemm_pass(
    f32x4* acc, const half_t* __restrict__ lhx,
    const half_t* bp0, const half_t* bp1, int lm, int lg)
{
    half8 bA[8], bB[8];
#pragma unroll
    for (int jt = 0; jt < 4; ++jt) {
        bA[jt]     = *reinterpret_cast<const half8*>(bp0 + jt * 4096);
        bA[4 + jt] = *reinterpret_cast<const half8*>(bp1 + jt * 4096);
    }
#pragma unroll 1
    for (int kt2 = 0; kt2 < 4; ++kt2) {
        const int kt = kt2 * 2;
        // prefetch b(kt+1); MFMA(kt) with bA
#pragma unroll
        for (int jt = 0; jt < 4; ++jt) {
            bB[jt]     = *reinterpret_cast<const half8*>(bp0 + jt * 4096 + (kt + 1) * 512);
            bB[4 + jt] = *reinterpret_cast<const half8*>(bp1 + jt * 4096 + (kt + 1) * 512);
        }
        {
            half8 a[2];
#pragma unroll
            for (int mt = 0; mt < 2; ++mt) {
                const int p = mt * 16 + lm;
                const int k = (kt * 32 + lg * 8) ^ ((p & 7) << 4);
                a[mt] = *reinterpret_cast<const half8*>(&lhx[p * 256 + k]);
            }
#pragma unroll
            for (int n = 0; n < 8; ++n)
#pragma unroll
                for (int mt = 0; mt < 2; ++mt)
                    acc[mt * 8 + n] = __builtin_amdgcn_mfma_f32_16x16x32_f16(
                        a[mt], bA[n], acc[mt * 8 + n], 0, 0, 0);
        }
        __builtin_amdgcn_sched_barrier(0);
        // prefetch b(kt+2) (wrap harmless); MFMA(kt+1) with bB
#pragma unroll
        for (int jt = 0; jt < 4; ++jt) {
            bA[jt]     = *reinterpret_cast<const half8*>(bp0 + jt * 4096 + ((kt + 2) & 7) * 512);
            bA[4 + jt] = *reinterpret_cast<const half8*>(bp1 + jt * 4096 + ((kt + 2) & 7) * 512);
        }
        {
            half8 a[2];
#pragma unroll
            for (int mt = 0; mt < 2; ++mt) {
                const int p = mt * 16 + lm;
                const int k = ((kt + 1) * 32 + lg * 8) ^ ((p & 7) << 4);
                a[mt] = *reinterpret_cast<const half8*>(&lhx[p * 256 + k]);
            }
#pragma unroll
            for (int n = 0; n < 8; ++n)
#pragma unroll
                for (int mt = 0; mt < 2; ++mt)
                    acc[mt * 8 + n] = __builtin_amdgcn_mfma_f32_16x16x32_f16(
                        a[mt], bB[n], acc[mt * 8 + n], 0, 0, 0);
        }
        __builtin_amdgcn_sched_barrier(0);
    }
}

// ---------------------------------------------------------------------------
// Persistent LSTM: block = 32 rows x 16 steps, 4 waves (256 threads),
// LDS = hx 16 KB + xp 64 KB = 80 KB -> TWO independent blocks per CU.
// R12 post-mortem: single 8-wave block is barrier-lockstepped, ~50% of each
// step neither MFMA nor VALU issues. Two blocks at independent phases fill
// each other's gaps (m114 overlap). Wave w owns h-cols [w*64, w*64+64).
// 2-pass gates (R5-validated): A=(f,o) -> cxr*=sig(f), og=f16 stash;
// B=(i,g) -> finish cell. Budget (256 unified/wave): acc 64 + b dbuf 64 +
// cxr 32 + og 16 + a 8 + misc ~30 = ~215.
// ---------------------------------------------------------------------------
__global__ __launch_bounds__(256, 2)
void lstm_kernel(
    const float* __restrict__ x,      // [8][256][1600]
    const float* __restrict__ hx0,    // [12800][256]
    const float* __restrict__ cx0,    // [12800][256]
    const float* __restrict__ b_ih,   // [1024]
    const float* __restrict__ b_hh,   // [1024]
    const float* __restrict__ W_lin,  // [2][256]
    const float* __restrict__ b_lin,  // [2]
    const half_t* __restrict__ Wih_s, // shuffled f16
    const half_t* __restrict__ Whh_s, // shuffled f16
    float* __restrict__ out)          // [12800][16][2]
{
    __shared__ __align__(16) half_t lds_hx[32 * 256];        // 16 KB
    __shared__ __align__(16) half_t lds_xp[4 * 32 * 64 * 4]; // 64 KB

    const int tid = threadIdx.x;
    const int w  = tid >> 6;   // wave 0..3 owns h-cols [w*64, w*64+64)
    const int l  = tid & 63;
    const int lm = l & 15;
    const int lg = l >> 4;
    const int w4 = w * 4;

    const int row0 = blockIdx.x * 32;     // 400 blocks * 32 rows
    const int bb_  = row0 / 1600;
    const int p0   = row0 % 1600;

    // ---- stage x tile into lds_hx, f16 swizzled ----
    {
        const float* xin = x + (size_t)bb_ * 409600 + p0;   // x[b][c][p0+p]
        for (int it = 0; it < 32; ++it) {
            int idx = it * 256 + tid;
            int p = idx & 31, c = idx >> 5;
            lds_hx[p * 256 + (c ^ ((p & 7) << 4))] = (half_t)xin[c * 1600 + p];
        }
    }
    __syncthreads();

    f32x4 acc[16];

    // ---- phase 0: x_proj = x @ W_ih^T + b_ih + b_hh, 2 passes -> LDS ----
#pragma unroll 1
    for (int pass = 0; pass < 2; ++pass) {
        const int base0 = pass ? 0 : 16;      // pass0:(f,o) pass1:(i,g)
        const int base1 = pass ? 32 : 48;
#pragma unroll
        for (int gi = 0; gi < 2; ++gi)
#pragma unroll
            for (int jt = 0; jt < 4; ++jt) {
                int col = ((gi ? base1 : base0) + w4 + jt) * 16 + lm;
                float bias = b_ih[col] + b_hh[col];
#pragma unroll
                for (int mt = 0; mt < 2; ++mt)
                    acc[mt * 8 + gi * 4 + jt] = (f32x4){bias, bias, bias, bias};
            }
        gemm_pass(acc, lds_hx,
                  Wih_s + (size_t)(base0 + w4) * 4096 + l * 8,
                  Wih_s + (size_t)(base1 + w4) * 4096 + l * 8, lm, lg);
#pragma unroll
        for (int n = 0; n < 8; ++n)
#pragma unroll
            for (int mt = 0; mt < 2; ++mt) {
                half4v xv;
#pragma unroll
                for (int r = 0; r < 4; ++r) xv[r] = (half_t)acc[mt * 8 + n][r];
                int f = pass * 16 + n * 2 + mt;
                *reinterpret_cast<half4v*>(
                    &lds_xp[((w * 32 + f) * 64 + l) * 4]) = xv;
            }
    }
    __syncthreads();   // x tile fully consumed, xp written

    // ---- stage h0 into lds_hx (coalesced on c); cx into registers ----
    {
        const float* hin = hx0 + (size_t)row0 * 256;
        for (int it = 0; it < 32; ++it) {
            int idx = it * 256 + tid;
            int c = idx & 255, p = idx >> 8;
            lds_hx[p * 256 + (c ^ ((p & 7) << 4))] = (half_t)hin[p * 256 + c];
        }
    }
    float cxr[32];
#pragma unroll
    for (int mt = 0; mt < 2; ++mt)
#pragma unroll
        for (int jt = 0; jt < 4; ++jt)
#pragma unroll
            for (int r = 0; r < 4; ++r) {
                int p = mt * 16 + lg * 4 + r;
                int c = w * 64 + jt * 16 + lm;
                cxr[(mt * 4 + jt) * 4 + r] = cx0[(size_t)(row0 + p) * 256 + c];
            }
    const float blin0 = b_lin[0], blin1 = b_lin[1];
    __syncthreads();

    // ---------------- 16 recurrent steps ----------------
#pragma unroll 1
    for (int t = 0; t < 16; ++t) {
        half4v og[8];   // o-gate preactivations, f16 (R5-validated)

        // ---- pass A: gates (f,o) ----
#pragma unroll
        for (int n = 0; n < 8; ++n)
#pragma unroll
            for (int mt = 0; mt < 2; ++mt) {
                half4v u = *reinterpret_cast<const half4v*>(
                    &lds_xp[((w * 32 + n * 2 + mt) * 64 + l) * 4]);
#pragma unroll
                for (int r = 0; r < 4; ++r) acc[mt * 8 + n][r] = (float)u[r];
            }
        __builtin_amdgcn_sched_barrier(0);
        gemm_pass(acc, lds_hx,
                  Whh_s + (size_t)(16 + w4) * 4096 + l * 8,
                  Whh_s + (size_t)(48 + w4) * 4096 + l * 8, lm, lg);
#pragma unroll
        for (int mt = 0; mt < 2; ++mt)
#pragma unroll
            for (int jt = 0; jt < 4; ++jt)
#pragma unroll
                for (int r = 0; r < 4; ++r) {
                    float fv = acc[mt * 8 + jt][r];
                    float ov = acc[mt * 8 + 4 + jt][r];
                    cxr[(mt * 4 + jt) * 4 + r] *= fast_sigmoid(fv);
                    og[mt * 4 + jt][r] = (half_t)ov;
                }
        __builtin_amdgcn_sched_barrier(0);

        // ---- pass B: gates (i,g) ----
#pragma unroll
        for (int n = 0; n < 8; ++n)
#pragma unroll
            for (int mt = 0; mt < 2; ++mt) {
                half4v u = *reinterpret_cast<const half4v*>(
                    &lds_xp[((w * 32 + 16 + n * 2 + mt) * 64 + l) * 4]);
#pragma unroll
                for (int r = 0; r < 4; ++r) acc[mt * 8 + n][r] = (float)u[r];
            }
        __builtin_amdgcn_sched_barrier(0);
        gemm_pass(acc, lds_hx,
                  Whh_s + (size_t)(w4) * 4096 + l * 8,
                  Whh_s + (size_t)(32 + w4) * 4096 + l * 8, lm, lg);

        __syncthreads();   // all waves finished reading lds_hx(t)

        // cell update; write hx(t+1) into lds_hx (f16, swizzled)
#pragma unroll
        for (int mt = 0; mt < 2; ++mt)
#pragma unroll
            for (int jt = 0; jt < 4; ++jt)
#pragma unroll
                for (int r = 0; r < 4; ++r) {
                    const int ci = (mt * 4 + jt) * 4 + r;
                    float iv = acc[mt * 8 + jt][r];
                    float gv = acc[mt * 8 + 4 + jt][r];
                    float cxn = cxr[ci] + fast_sigmoid(iv) * fast_tanh(gv);
                    cxr[ci] = cxn;
                    float so = fast_sigmoid((float)og[mt * 4 + jt][r]);
                    float h = so * fast_tanh(cxn);
                    int p  = mt * 16 + lg * 4 + r;
                    int cc = w * 64 + jt * 16 + lm;
                    lds_hx[p * 256 + (cc ^ ((p & 7) << 4))] = (half_t)h;
                }
        __syncthreads();   // hx(t+1) visible to all

        // head: y = leaky_relu(hx) @ W_lin^T + b_lin -> [n][t][o]
        {
            const int p = tid >> 3;          // row 0..31
            const int o = (tid >> 2) & 1;    // output 0..1
            const int q = tid & 3;           // quarter of the 256 h-cols
            const float* wl = W_lin + o * 256 + q * 64;
            asm volatile("" : "+v"(wl));     // defeat 32-reg W_lin LICM
            float s = 0.0f;
#pragma unroll 2
            for (int cb = 0; cb < 16; ++cb) {
                int c0 = q * 64 + cb * 4;
                half4v u = *reinterpret_cast<const half4v*>(
                    &lds_hx[p * 256 + (c0 ^ ((p & 7) << 4))]);
                float4 wv = *reinterpret_cast<const float4*>(wl + cb * 4);
                float h0 = (float)u[0], h1 = (float)u[1];
                float h2 = (float)u[2], h3 = (float)u[3];
                s += fmaxf(h0, 0.01f * h0) * wv.x;
                s += fmaxf(h1, 0.01f * h1) * wv.y;
                s += fmaxf(h2, 0.01f * h2) * wv.z;
                s += fmaxf(h3, 0.01f * h3) * wv.w;
            }
            s += __shfl_xor(s, 1);
            s += __shfl_xor(s, 2);
            if (q == 0)
                out[((size_t)(row0 + p) * 16 + t) * 2 + o] =
                    s + (o ? blin1 : blin0);
        }
    }
}

// ---------------------------------------------------------------------------
extern "C" void kernel_launch(void* const* d_in, const int* in_sizes, int n_in,
                              void* d_out, int out_size, void* d_ws, size_t ws_size,
                              hipStream_t stream)
{
    const float* x    = (const float*)d_in[0];
    const float* hx   = (const float*)d_in[1];
    const float* cx   = (const float*)d_in[2];
    const float* Wih  = (const float*)d_in[3];
    const float* Whh  = (const float*)d_in[4];
    const float* bih  = (const float*)d_in[5];
    const float* bhh  = (const float*)d_in[6];
    const float* Wlin = (const float*)d_in[7];
    const float* blin = (const float*)d_in[8];
    float* out = (float*)d_out;

    half_t* wih_s = (half_t*)d_ws;             // 512 KB
    half_t* whh_s = wih_s + 1024 * 256;        // 512 KB

    shuffle_w_kernel<<<512, 64, 0, stream>>>(Wih, wih_s);
    shuffle_w_kernel<<<512, 64, 0, stream>>>(Whh, whh_s);
    lstm_kernel<<<400, 256, 0, stream>>>(x, hx, cx, bih, bhh, Wlin, blin,
                                         wih_s, whh_s, out);
}

// Round 14
// 253.562 us; speedup vs baseline: 1.5297x; 1.5297x over previous
//
#include <hip/hip_runtime.h>
#include <stdint.h>
#include <stddef.h>

// ---------- types ----------
typedef _Float16 half_t;
typedef half_t half8  __attribute__((ext_vector_type(8)));
typedef half_t half4v __attribute__((ext_vector_type(4)));
typedef float  f32x4  __attribute__((ext_vector_type(4)));

__device__ __forceinline__ float fast_sigmoid(float x) {
    float e = __builtin_amdgcn_exp2f(-1.44269504f * x);
    return __builtin_amdgcn_rcpf(1.0f + e);
}
__device__ __forceinline__ float fast_tanh(float x) {
    float e = __builtin_amdgcn_exp2f(2.88539008f * x);
    return 1.0f - 2.0f * __builtin_amdgcn_rcpf(1.0f + e);
}

// ---------------------------------------------------------------------------
// Prep: W [1024][256] f32 row-major -> MFMA-B fragment order, f16.
// Bijection (contiguous k): lane l, elem e of tile (T,kt) holds
//   B[k = kt*32 + (l>>4)*8 + e, j = T*16 + (l&15)].
// A-fragments from LDS use the SAME mapping (validated R1-R13, absmax 2e-3).
// ---------------------------------------------------------------------------
__global__ __launch_bounds__(64) void shuffle_w_kernel(
    const float* __restrict__ W, half_t* __restrict__ out)
{
    const int blk = blockIdx.x;         // 512 = 64 T * 8 kt
    const int T = blk >> 3, kt = blk & 7;
    const int l = threadIdx.x;
    const int j = T * 16 + (l & 15);
    const int k0 = kt * 32 + ((l >> 4) << 3);
    half8 v;
#pragma unroll
    for (int e = 0; e < 8; ++e) v[e] = (half_t)W[j * 256 + k0 + e];
    *reinterpret_cast<half8*>(out + (size_t)(blk * 64 + l) * 8) = v;
}

// ---------------------------------------------------------------------------
// 2-gate (4 N-tile) GEMM pass with B double-buffer prefetch (R12-validated,
// best config so far). kt loop pinned; b(kt+1) issued before MFMA(kt) so
// L2 latency hides under the 16-MFMA block.
// R14: Ws made opaque at entry -- stops LICM hoisting both passes' bp[4]
// arrays (16 regs) across the entire t-loop.
// ---------------------------------------------------------------------------
__device__ __forceinline__ void gemm_pass(
    f32x4* acc, const half_t* __restrict__ lhx,
    const half_t* Ws, int Ta, int Tb, int Tc, int Td,
    int lm, int lg, int l)
{
    asm volatile("" : "+v"(Ws));   // anti-LICM: recompute bp per call
    const half_t* bp[4] = {
        Ws + (size_t)((Ta * 8) * 64 + l) * 8,
        Ws + (size_t)((Tb * 8) * 64 + l) * 8,
        Ws + (size_t)((Tc * 8) * 64 + l) * 8,
        Ws + (size_t)((Td * 8) * 64 + l) * 8 };
    half8 bA[4], bB[4];
#pragma unroll
    for (int n = 0; n < 4; ++n) bA[n] = *reinterpret_cast<const half8*>(bp[n]);

#pragma unroll 1
    for (int kt2 = 0; kt2 < 4; ++kt2) {
        const int kt = kt2 * 2;
        // prefetch b(kt+1); MFMA(kt) with bA
#pragma unroll
        for (int n = 0; n < 4; ++n)
            bB[n] = *reinterpret_cast<const half8*>(bp[n] + (kt + 1) * 512);
        {
            half8 a[4];
#pragma unroll
            for (int mt = 0; mt < 4; ++mt) {
                const int p = mt * 16 + lm;
                const int k = (kt * 32 + lg * 8) ^ ((p & 7) << 4);
                a[mt] = *reinterpret_cast<const half8*>(&lhx[p * 256 + k]);
            }
#pragma unroll
            for (int n = 0; n < 4; ++n)
#pragma unroll
                for (int mt = 0; mt < 4; ++mt)
                    acc[mt * 4 + n] = __builtin_amdgcn_mfma_f32_16x16x32_f16(
                        a[mt], bA[n], acc[mt * 4 + n], 0, 0, 0);
        }
        __builtin_amdgcn_sched_barrier(0);
        // prefetch b(kt+2) (wrap harmless); MFMA(kt+1) with bB
#pragma unroll
        for (int n = 0; n < 4; ++n)
            bA[n] = *reinterpret_cast<const half8*>(bp[n] + ((kt + 2) & 7) * 512);
        {
            half8 a[4];
#pragma unroll
            for (int mt = 0; mt < 4; ++mt) {
                const int p = mt * 16 + lm;
                const int k = ((kt + 1) * 32 + lg * 8) ^ ((p & 7) << 4);
                a[mt] = *reinterpret_cast<const half8*>(&lhx[p * 256 + k]);
            }
#pragma unroll
            for (int n = 0; n < 4; ++n)
#pragma unroll
                for (int mt = 0; mt < 4; ++mt)
                    acc[mt * 4 + n] = __builtin_amdgcn_mfma_f32_16x16x32_f16(
                        a[mt], bB[n], acc[mt * 4 + n], 0, 0, 0);
        }
        __builtin_amdgcn_sched_barrier(0);
    }
}

// ---------------------------------------------------------------------------
// Persistent LSTM: block = 64 rows x 16 steps, 8 waves (512 threads).
// R12 structure (best: 284 us) + R14 spill fixes. R12's residual ~8-slot
// spill traced to the acc-init ds_read batch: 16 ds_read_b64 issued before
// any cvt -> 32 transient arch regs on top of b-dbuf 32 + cxr 32 + og 16 +
// addr ~20 = ~132 > 128 arch cap. Fix: chunk the init 4-frags-at-a-time
// with sched_barrier(0) (transient <= 8). Plus anti-LICM in gemm_pass.
// LDS: hx 32 KB (XOR-swizzled) + xp 128 KB = 160 KB, 1 blk/CU.
// ---------------------------------------------------------------------------
__global__ __launch_bounds__(512)
void lstm_kernel(
    const float* __restrict__ x,      // [8][256][1600]
    const float* __restrict__ hx0,    // [12800][256]
    const float* __restrict__ cx0,    // [12800][256]
    const float* __restrict__ b_ih,   // [1024]
    const float* __restrict__ b_hh,   // [1024]
    const float* __restrict__ W_lin,  // [2][256]
    const float* __restrict__ b_lin,  // [2]
    const half_t* __restrict__ Wih_s, // shuffled f16
    const half_t* __restrict__ Whh_s, // shuffled f16
    float* __restrict__ out)          // [12800][16][2]
{
    __shared__ __align__(16) half_t lds_hx[64 * 256];        // 32 KB
    __shared__ __align__(16) half_t lds_xp[8 * 32 * 64 * 4]; // 128 KB

    const int tid = threadIdx.x;
    const int w  = tid >> 6;   // wave 0..7 owns h-cols [w*32, w*32+32)
    const int l  = tid & 63;
    const int lm = l & 15;
    const int lg = l >> 4;
    const int w2 = w * 2;

    const int row0 = blockIdx.x * 64;     // 200 blocks * 64 rows
    const int bb_  = row0 / 1600;
    const int p0   = row0 % 1600;

    // ---- stage x tile into lds_hx, f16 swizzled (coalesced on p) ----
    {
        const float* xin = x + (size_t)bb_ * 409600 + p0;   // x[b][c][p0+p]
        for (int it = 0; it < 32; ++it) {
            int idx = it * 512 + tid;
            int p = idx & 63, c = idx >> 6;
            lds_hx[p * 256 + (c ^ ((p & 7) << 4))] = (half_t)xin[c * 1600 + p];
        }
    }
    __syncthreads();

    f32x4 acc[16];

    // ---- phase 0: x_proj = x @ W_ih^T + b_ih + b_hh, 2 passes -> LDS ----
#pragma unroll 1
    for (int pass = 0; pass < 2; ++pass) {
        const int gA = pass ? 0 : 16;     // pass0:(f,o) pass1:(i,g)
        const int gB = pass ? 32 : 48;
        const int Ta = gA + w2, Tb = Ta + 1;
        const int Tc = gB + w2, Td = Tc + 1;
        const int Tt[4] = {Ta, Tb, Tc, Td};
#pragma unroll
        for (int n = 0; n < 4; ++n) {
            int col = Tt[n] * 16 + lm;
            float bias = b_ih[col] + b_hh[col];
#pragma unroll
            for (int mt = 0; mt < 4; ++mt)
                acc[mt * 4 + n] = (f32x4){bias, bias, bias, bias};
        }
        gemm_pass(acc, lds_hx, Wih_s, Ta, Tb, Tc, Td, lm, lg, l);
#pragma unroll
        for (int f = 0; f < 16; ++f) {
            half4v xv;
#pragma unroll
            for (int r = 0; r < 4; ++r) xv[r] = (half_t)acc[f][r];
            *reinterpret_cast<half4v*>(
                &lds_xp[((w * 32 + pass * 16 + f) * 64 + l) * 4]) = xv;
        }
    }
    __syncthreads();   // x tile fully consumed, xp written

    // ---- stage h0 into lds_hx (coalesced on c); cx into registers ----
    {
        const float* hin = hx0 + (size_t)row0 * 256;
        for (int it = 0; it < 32; ++it) {
            int idx = it * 512 + tid;
            int c = idx & 255, p = idx >> 8;
            lds_hx[p * 256 + (c ^ ((p & 7) << 4))] = (half_t)hin[p * 256 + c];
        }
    }
    float cxr[32];
#pragma unroll
    for (int mt = 0; mt < 4; ++mt)
#pragma unroll
        for (int j = 0; j < 2; ++j)
#pragma unroll
            for (int r = 0; r < 4; ++r) {
                int p = mt * 16 + lg * 4 + r;
                int c = w * 32 + j * 16 + lm;
                cxr[(mt * 2 + j) * 4 + r] = cx0[(size_t)(row0 + p) * 256 + c];
            }
    const float blin0 = b_lin[0], blin1 = b_lin[1];
    __syncthreads();

    // ---------------- 16 recurrent steps ----------------
#pragma unroll 1
    for (int t = 0; t < 16; ++t) {
        half4v og[8];   // o-gate preactivations, f16 (R5-validated)

        // ---- pass A: gates (f,o); acc init CHUNKED (4 frags/fence) ----
#pragma unroll
        for (int fc = 0; fc < 16; fc += 4) {
#pragma unroll
            for (int f = fc; f < fc + 4; ++f) {
                half4v u = *reinterpret_cast<const half4v*>(
                    &lds_xp[((w * 32 + f) * 64 + l) * 4]);
#pragma unroll
                for (int r = 0; r < 4; ++r) acc[f][r] = (float)u[r];
            }
            __builtin_amdgcn_sched_barrier(0);
        }
        gemm_pass(acc, lds_hx, Whh_s, 16 + w2, 17 + w2, 48 + w2, 49 + w2,
                  lm, lg, l);
#pragma unroll
        for (int mt = 0; mt < 4; ++mt)
#pragma unroll
            for (int j = 0; j < 2; ++j)
#pragma unroll
                for (int r = 0; r < 4; ++r) {
                    float fv = acc[mt * 4 + 0 + j][r];
                    float ov = acc[mt * 4 + 2 + j][r];
                    cxr[(mt * 2 + j) * 4 + r] *= fast_sigmoid(fv);
                    og[mt * 2 + j][r] = (half_t)ov;
                }
        __builtin_amdgcn_sched_barrier(0);

        // ---- pass B: gates (i,g); acc init CHUNKED ----
#pragma unroll
        for (int fc = 0; fc < 16; fc += 4) {
#pragma unroll
            for (int f = fc; f < fc + 4; ++f) {
                half4v u = *reinterpret_cast<const half4v*>(
                    &lds_xp[((w * 32 + 16 + f) * 64 + l) * 4]);
#pragma unroll
                for (int r = 0; r < 4; ++r) acc[f][r] = (float)u[r];
            }
            __builtin_amdgcn_sched_barrier(0);
        }
        gemm_pass(acc, lds_hx, Whh_s, w2, w2 + 1, 32 + w2, 33 + w2,
                  lm, lg, l);

        __syncthreads();   // all waves finished reading lds_hx(t)

        // cell update; write hx(t+1) into lds_hx (f16, swizzled)
#pragma unroll
        for (int mt = 0; mt < 4; ++mt)
#pragma unroll
            for (int j = 0; j < 2; ++j)
#pragma unroll
                for (int r = 0; r < 4; ++r) {
                    const int ci = (mt * 2 + j) * 4 + r;
                    float iv = acc[mt * 4 + 0 + j][r];
                    float gv = acc[mt * 4 + 2 + j][r];
                    float cxn = cxr[ci] + fast_sigmoid(iv) * fast_tanh(gv);
                    cxr[ci] = cxn;
                    float so = fast_sigmoid((float)og[mt * 2 + j][r]);
                    float h = so * fast_tanh(cxn);
                    int p  = mt * 16 + lg * 4 + r;
                    int cc = w * 32 + j * 16 + lm;
                    lds_hx[p * 256 + (cc ^ ((p & 7) << 4))] = (half_t)h;
                }
        __syncthreads();   // hx(t+1) visible to all

        // head: y = leaky_relu(hx) @ W_lin^T + b_lin -> [n][t][o]
        {
            const int p = tid >> 3;          // row 0..63
            const int o = (tid >> 2) & 1;    // output 0..1
            const int q = tid & 3;           // quarter of the 256 h-cols
            const float* wl = W_lin + o * 256 + q * 64;
            asm volatile("" : "+v"(wl));     // defeat 32-reg W_lin LICM
            float s = 0.0f;
#pragma unroll 2
            for (int cb = 0; cb < 16; ++cb) {
                int c0 = q * 64 + cb * 4;
                half4v u = *reinterpret_cast<const half4v*>(
                    &lds_hx[p * 256 + (c0 ^ ((p & 7) << 4))]);
                float4 wv = *reinterpret_cast<const float4*>(wl + cb * 4);
                float h0 = (float)u[0], h1 = (float)u[1];
                float h2 = (float)u[2], h3 = (float)u[3];
                s += fmaxf(h0, 0.01f * h0) * wv.x;
                s += fmaxf(h1, 0.01f * h1) * wv.y;
                s += fmaxf(h2, 0.01f * h2) * wv.z;
                s += fmaxf(h3, 0.01f * h3) * wv.w;
            }
            s += __shfl_xor(s, 1);
            s += __shfl_xor(s, 2);
            if (q == 0)
                out[((size_t)(row0 + p) * 16 + t) * 2 + o] =
                    s + (o ? blin1 : blin0);
        }
    }
}

// ---------------------------------------------------------------------------
extern "C" void kernel_launch(void* const* d_in, const int* in_sizes, int n_in,
                              void* d_out, int out_size, void* d_ws, size_t ws_size,
                              hipStream_t stream)
{
    const float* x    = (const float*)d_in[0];
    const float* hx   = (const float*)d_in[1];
    const float* cx   = (const float*)d_in[2];
    const float* Wih  = (const float*)d_in[3];
    const float* Whh  = (const float*)d_in[4];
    const float* bih  = (const float*)d_in[5];
    const float* bhh  = (const float*)d_in[6];
    const float* Wlin = (const float*)d_in[7];
    const float* blin = (const float*)d_in[8];
    float* out = (float*)d_out;

    half_t* wih_s = (half_t*)d_ws;             // 512 KB
    half_t* whh_s = wih_s + 1024 * 256;        // 512 KB

    shuffle_w_kernel<<<512, 64, 0, stream>>>(Wih, wih_s);
    shuffle_w_kernel<<<512, 64, 0, stream>>>(Whh, whh_s);
    lstm_kernel<<<200, 512, 0, stream>>>(x, hx, cx, bih, bhh, Wlin, blin,
                                         wih_s, whh_s, out);
}